// Round 3
// baseline (267.304 us; speedup 1.0000x reference)
//
#include <hip/hip_runtime.h>
#include <hip/hip_bf16.h>
#include <math.h>

#define NROW 8192
#define DDIM 256
#define BM 128
#define BN 128
#define BK 64
#define NT_SYM 2080    // 64*65/2 lower-triangular 128x128 tiles
#define NT_FULL 4096

typedef __attribute__((ext_vector_type(8))) short bf16x8;
typedef __attribute__((ext_vector_type(4))) float f32x4;
typedef __attribute__((address_space(3))) unsigned int lds_u32;
typedef const __attribute__((address_space(1))) unsigned int glb_u32;

static __device__ inline unsigned short f2bf(float x) {
    union { float f; unsigned int u; } v; v.f = x;
    unsigned int r = v.u + 0x7fffu + ((v.u >> 16) & 1u);  // RNE
    return (unsigned short)(r >> 16);
}

// One wave per row: L2-normalize H1/H2 rows, scale by sqrt(2*log2(e)) so the
// bf16 Gram entries come out as 2*log2(e)*s  ->  exp(2s) == exp2(acc).
// diag[row] = 2*dot(z1n,z2n) fp32 (unscaled). Also zero-inits rowsum arrays.
__global__ __launch_bounds__(256) void normalize_kernel(
        const float* __restrict__ h1, const float* __restrict__ h2,
        unsigned short* __restrict__ z1b, unsigned short* __restrict__ z2b,
        float* __restrict__ diag,
        float* __restrict__ rs1, float* __restrict__ rs2,
        float* __restrict__ rbr, float* __restrict__ rbc) {
    int wave = threadIdx.x >> 6;
    int lane = threadIdx.x & 63;
    int row  = blockIdx.x * 4 + wave;
    const float4* p1 = (const float4*)(h1 + (size_t)row * DDIM);
    const float4* p2 = (const float4*)(h2 + (size_t)row * DDIM);
    float4 a = p1[lane];
    float4 b = p2[lane];
    float s1 = a.x*a.x + a.y*a.y + a.z*a.z + a.w*a.w;
    float s2 = b.x*b.x + b.y*b.y + b.z*b.z + b.w*b.w;
    #pragma unroll
    for (int m = 1; m < 64; m <<= 1) { s1 += __shfl_xor(s1, m); s2 += __shfl_xor(s2, m); }
    float r1 = 1.0f / fmaxf(sqrtf(s1), 1e-12f);
    float r2 = 1.0f / fmaxf(sqrtf(s2), 1e-12f);
    float n1x = a.x*r1, n1y = a.y*r1, n1z = a.z*r1, n1w = a.w*r1;
    float n2x = b.x*r2, n2y = b.y*r2, n2z = b.z*r2, n2w = b.w*r2;
    float dt = n1x*n2x + n1y*n2y + n1z*n2z + n1w*n2w;
    #pragma unroll
    for (int m = 1; m < 64; m <<= 1) dt += __shfl_xor(dt, m);
    if (lane == 0) {
        diag[row] = 2.0f * dt;
        rs1[row] = 0.f; rs2[row] = 0.f; rbr[row] = 0.f; rbc[row] = 0.f;
    }
    const float SC = 1.69864364f;   // sqrt(2 * log2(e))
    ushort4 o1, o2;
    o1.x = f2bf(n1x*SC); o1.y = f2bf(n1y*SC); o1.z = f2bf(n1z*SC); o1.w = f2bf(n1w*SC);
    o2.x = f2bf(n2x*SC); o2.y = f2bf(n2y*SC); o2.z = f2bf(n2z*SC); o2.w = f2bf(n2w*SC);
    ((ushort4*)(z1b + (size_t)row * DDIM))[lane] = o1;
    ((ushort4*)(z2b + (size_t)row * DDIM))[lane] = o2;
}

// DMA one 128x64 A-tile + 128x64 B-tile (k-offset kt) into the given buffers.
// 8 global_load_lds instructions per thread -> vmcnt += 8.
#define ISSUE_DMA(kt, bufA, bufB)                                                        \
    {                                                                                    \
        _Pragma("unroll")                                                                \
        for (int p = 0; p < 4; ++p) {                                                    \
            int r0 = (p * 4 + wid) * 8;                                                  \
            const unsigned short* ga = Ap + (size_t)(rt + r0 + srow) * DDIM + (kt) + gcol0; \
            __builtin_amdgcn_global_load_lds((glb_u32*)ga, (lds_u32*)((bufA) + r0 * BK), 16, 0, 0); \
            const unsigned short* gb = Bp + (size_t)(ct + r0 + srow) * DDIM + (kt) + gcol0; \
            __builtin_amdgcn_global_load_lds((glb_u32*)gb, (lds_u32*)((bufB) + r0 * BK), 16, 0, 0); \
        }                                                                                \
    }

// Consume one staged k-tile: 2 ks-steps x (8 ds_read_b128 + 16 MFMA).
#define COMPUTE(bufA, bufB)                                                              \
    {                                                                                    \
        _Pragma("unroll")                                                                \
        for (int ks = 0; ks < 2; ++ks) {                                                 \
            bf16x8 af[4], bfr[4];                                                        \
            _Pragma("unroll")                                                            \
            for (int mi = 0; mi < 4; ++mi) {                                             \
                int r = wr * 64 + mi * 16 + l15;                                         \
                int slot = (ks * 4 + quad) ^ (l15 & 7);                                  \
                af[mi] = *((const bf16x8*)((bufA) + r * BK + slot * 8));                 \
            }                                                                            \
            _Pragma("unroll")                                                            \
            for (int ni = 0; ni < 4; ++ni) {                                             \
                int c = wc * 64 + ni * 16 + l15;                                         \
                int slot = (ks * 4 + quad) ^ (l15 & 7);                                  \
                bfr[ni] = *((const bf16x8*)((bufB) + c * BK + slot * 8));                \
            }                                                                            \
            _Pragma("unroll")                                                            \
            for (int mi = 0; mi < 4; ++mi)                                               \
                _Pragma("unroll")                                                        \
                for (int ni = 0; ni < 4; ++ni)                                           \
                    acc[mi][ni] = __builtin_amdgcn_mfma_f32_16x16x32_bf16(               \
                        af[mi], bfr[ni], acc[mi][ni], 0, 0, 0);                          \
        }                                                                                \
    }

#define WAIT_VM8()  __builtin_amdgcn_s_waitcnt(0x0F78)   // vmcnt(8), lgkm/exp open
#define WAIT_VM0()  __builtin_amdgcn_s_waitcnt(0x0F70)   // vmcnt(0)
#define BARRIER()   __builtin_amdgcn_s_barrier()

// Tiles: b < 2080 -> S11 lower-tri; < 4160 -> S22 lower-tri; else S12 full.
// Double-buffered DMA pipeline: tile k+1 is in flight while tile k computes;
// barriers wait vmcnt(8) (not 0) so the prefetch never drains.
__global__ __launch_bounds__(256, 2) void expsum_kernel(
        const unsigned short* __restrict__ z1, const unsigned short* __restrict__ z2,
        float* __restrict__ rs1, float* __restrict__ rs2,
        float* __restrict__ rbr, float* __restrict__ rbc) {
    int b = blockIdx.x;
    int kind, t;
    if (b < NT_SYM)            { kind = 0; t = b; }
    else if (b < 2 * NT_SYM)   { kind = 1; t = b - NT_SYM; }
    else                       { kind = 2; t = b - 2 * NT_SYM; }

    int by, bx;
    const unsigned short *Ap, *Bp;
    float *rowsum, *colsum;
    if (kind == 2) {
        by = t >> 6; bx = t & 63;
        Ap = z1; Bp = z2; rowsum = rbr; colsum = rbc;
    } else {
        by = (int)((sqrtf(8.0f * (float)t + 1.0f) - 1.0f) * 0.5f);
        while ((by + 1) * (by + 2) / 2 <= t) ++by;
        while (by * (by + 1) / 2 > t) --by;
        bx = t - by * (by + 1) / 2;          // bx <= by
        const unsigned short* z = (kind == 0) ? z1 : z2;
        Ap = z; Bp = z;
        rowsum = (kind == 0) ? rs1 : rs2;
        colsum = (bx == by) ? nullptr : rowsum;
    }

    const int rt = by * BM;
    const int ct = bx * BN;

    __shared__ __align__(16) unsigned short lA0[BM * BK];  // 4 x 16 KB = 64 KB
    __shared__ __align__(16) unsigned short lB0[BN * BK];
    __shared__ __align__(16) unsigned short lA1[BM * BK];
    __shared__ __align__(16) unsigned short lB1[BN * BK];

    const int tid  = threadIdx.x;
    const int lane = tid & 63;
    const int wid  = tid >> 6;
    const int wr   = wid >> 1;
    const int wc   = wid & 1;
    const int quad = lane >> 4;
    const int l15  = lane & 15;

    const int srow   = lane >> 3;
    const int schunk = (lane & 7) ^ srow;     // XOR swizzle on global side
    const int gcol0  = schunk * 8;

    f32x4 acc[4][4];
    #pragma unroll
    for (int mi = 0; mi < 4; ++mi)
        #pragma unroll
        for (int ni = 0; ni < 4; ++ni)
            acc[mi][ni] = (f32x4){0.f, 0.f, 0.f, 0.f};

    // Pipeline: D0 D1 | W8 B C0 | B D2 W8 B C1 | B D3 W8 B C2 | W0 B C3
    ISSUE_DMA(0,   lA0, lB0);
    ISSUE_DMA(64,  lA1, lB1);
    WAIT_VM8(); BARRIER();
    COMPUTE(lA0, lB0);
    BARRIER();                      // all waves done reading buf0
    ISSUE_DMA(128, lA0, lB0);
    WAIT_VM8(); BARRIER();
    COMPUTE(lA1, lB1);
    BARRIER();                      // all waves done reading buf1
    ISSUE_DMA(192, lA1, lB1);
    WAIT_VM8(); BARRIER();          // tile2 landed (tile3 still in flight)
    COMPUTE(lA0, lB0);
    WAIT_VM0(); BARRIER();          // tile3 landed
    COMPUTE(lA1, lB1);

    // C/D layout: col = lane&15, row = quad*4 + reg. acc = 2*log2e*s -> exp2.
    float colpart[4] = {0.f, 0.f, 0.f, 0.f};
    #pragma unroll
    for (int mi = 0; mi < 4; ++mi) {
        #pragma unroll
        for (int r = 0; r < 4; ++r) {
            float rp = 0.f;
            #pragma unroll
            for (int ni = 0; ni < 4; ++ni) {
                float e = exp2f(acc[mi][ni][r]);
                rp += e;
                colpart[ni] += e;
            }
            rp += __shfl_xor(rp, 1);
            rp += __shfl_xor(rp, 2);
            rp += __shfl_xor(rp, 4);
            rp += __shfl_xor(rp, 8);
            if (l15 == 0) {
                int grow = rt + wr * 64 + mi * 16 + quad * 4 + r;
                atomicAdd(&rowsum[grow], rp);
            }
        }
    }
    if (colsum) {
        #pragma unroll
        for (int ni = 0; ni < 4; ++ni) {
            float cp = colpart[ni];
            cp += __shfl_xor(cp, 16);
            cp += __shfl_xor(cp, 32);
            if (lane < 16) {
                int gcol = ct + wc * 64 + ni * 16 + l15;
                atomicAdd(&colsum[gcol], cp);
            }
        }
    }
}

// 32 blocks x 256 threads, one row each; block-reduce then one atomicAdd.
__global__ __launch_bounds__(256) void finalize_kernel(
        const float* __restrict__ rs1, const float* __restrict__ rs2,
        const float* __restrict__ rbr, const float* __restrict__ rbc,
        const float* __restrict__ diag, float* __restrict__ out) {
    __shared__ float s4[4];
    const float E2 = 7.38905609893065f;   // exp(1/tau), tau=0.5
    int i = blockIdx.x * 256 + threadIdx.x;
    float den1 = rs1[i] + rbr[i] - E2;
    float den2 = rs2[i] + rbc[i] - E2;
    float v = 0.5f * (logf(den1) + logf(den2)) - diag[i];
    #pragma unroll
    for (int m = 1; m < 64; m <<= 1) v += __shfl_xor(v, m);
    if ((threadIdx.x & 63) == 0) s4[threadIdx.x >> 6] = v;
    __syncthreads();
    if (threadIdx.x == 0) {
        float t = (s4[0] + s4[1] + s4[2] + s4[3]) * (1.0f / (float)NROW);
        atomicAdd(out, t);
    }
}

extern "C" void kernel_launch(void* const* d_in, const int* in_sizes, int n_in,
                              void* d_out, int out_size, void* d_ws, size_t ws_size,
                              hipStream_t stream) {
    const float* h1 = (const float*)d_in[0];
    const float* h2 = (const float*)d_in[1];
    float* out = (float*)d_out;

    char* ws = (char*)d_ws;
    unsigned short* z1b = (unsigned short*)ws;                                // 4 MB
    unsigned short* z2b = (unsigned short*)(ws + (size_t)NROW * DDIM * 2);    // 4 MB
    float* sums = (float*)(ws + (size_t)2 * NROW * DDIM * 2);
    float* rs1  = sums;
    float* rs2  = sums + NROW;
    float* rbr  = sums + 2 * NROW;
    float* rbc  = sums + 3 * NROW;
    float* diag = sums + 4 * NROW;

    hipMemsetAsync(out, 0, sizeof(float), stream);

    normalize_kernel<<<NROW / 4, 256, 0, stream>>>(h1, h2, z1b, z2b, diag,
                                                   rs1, rs2, rbr, rbc);

    expsum_kernel<<<2 * NT_SYM + NT_FULL, 256, 0, stream>>>(z1b, z2b, rs1, rs2, rbr, rbc);

    finalize_kernel<<<NROW / 256, 256, 0, stream>>>(rs1, rs2, rbr, rbc, diag, out);
}